// Round 6
// baseline (736.261 us; speedup 1.0000x reference)
//
#include <hip/hip_runtime.h>

// ---------------- helpers ----------------
__device__ __forceinline__ float bf1(unsigned short s){ return __uint_as_float((unsigned)s << 16); }
__device__ __forceinline__ unsigned short f2bf(float f){
  unsigned u = __float_as_uint(f);
  u += 0x7fffu + ((u >> 16) & 1u);   // RNE
  return (unsigned short)(u >> 16);
}
// packed f32x2 -> bf16x2 (lo = a, hi = b), RNE — single VALU instr
__device__ __forceinline__ unsigned cvt_pk_bf16(float a, float b){
  unsigned r;
  asm("v_cvt_pk_bf16_f32 %0, %1, %2" : "=v"(r) : "v"(a), "v"(b));
  return r;
}

typedef __attribute__((ext_vector_type(8))) short short8;
typedef __attribute__((ext_vector_type(4))) float f32x4;

__device__ __forceinline__ f32x4 mfma16(short8 a, short8 b, f32x4 c){
  return __builtin_amdgcn_mfma_f32_16x16x32_bf16(a, b, c, 0, 0, 0);
}

#define GLOAD_LDS16(g, l) \
  __builtin_amdgcn_global_load_lds((const __attribute__((address_space(1))) unsigned int*)(g), \
                                   (__attribute__((address_space(3))) unsigned int*)(l), 16, 0, 0)

// ---------------- kernel 1: LayerNorm over d_m + transpose msa[c][n][l] -> x[l][n][c] (bf16) ----------------
__global__ __launch_bounds__(256) void ln_msa_kernel(
    const float* __restrict__ msa, const float* __restrict__ gam,
    const float* __restrict__ bet, unsigned short* __restrict__ x16)
{
  __shared__ float tile[256*33];          // [c][l] pitch 33
  __shared__ float ps[8*32], pq[8*32];
  __shared__ float mean_s[32], rstd_s[32];
  const int t = threadIdx.x;
  const int l0 = blockIdx.x * 32;
  const int n  = blockIdx.y;
  {
    const int lt = t & 31, ct = t >> 5;
    for (int r = 0; r < 32; ++r) {
      int c = r*8 + ct;
      tile[c*33 + lt] = msa[(size_t)c*131072 + (size_t)n*1024 + l0 + lt];
    }
  }
  __syncthreads();
  {
    const int lt = t & 31, cp = t >> 5;
    float s1 = 0.f, s2 = 0.f;
    for (int cc = 0; cc < 32; ++cc) {
      int c = cp*32 + ((cc + cp*4) & 31);
      float v = tile[c*33 + lt];
      s1 += v; s2 += v*v;
    }
    ps[cp*32 + lt] = s1; pq[cp*32 + lt] = s2;
  }
  __syncthreads();
  if (t < 32) {
    float s1 = 0.f, s2 = 0.f;
    for (int cp = 0; cp < 8; ++cp){ s1 += ps[cp*32+t]; s2 += pq[cp*32+t]; }
    float m = s1 * (1.f/256.f);
    float v = s2 * (1.f/256.f) - m*m;
    mean_s[t] = m;
    rstd_s[t] = rsqrtf(v + 1e-5f);
  }
  __syncthreads();
  {
    const float g = gam[t], b = bet[t];
    for (int l = 0; l < 32; ++l) {
      float v = (tile[t*33 + l] - mean_s[l]) * rstd_s[l] * g + b;
      x16[((size_t)(l0+l)*128 + n)*256 + t] = f2bf(v);
    }
  }
}

// ---------------- kernel 2: pair bias = LN(pairs) @ Wb -> bias[h][i][j] fp32 ----------------
__global__ __launch_bounds__(64) void pair_bias_kernel(
    const float* __restrict__ pairs, const float* __restrict__ gam,
    const float* __restrict__ bet, const float* __restrict__ Wb,
    float* __restrict__ biasb)
{
  const int j = blockIdx.x, i = blockIdx.y;
  const int t = threadIdx.x;
  const float* row = pairs + ((size_t)i*128 + j)*128;
  float v0 = row[t], v1 = row[t+64];
  float s = v0 + v1;
  #pragma unroll
  for (int o = 1; o < 64; o <<= 1) s += __shfl_xor(s, o, 64);
  float m = s * (1.f/128.f);
  float d0 = v0 - m, d1 = v1 - m;
  float q = d0*d0 + d1*d1;
  #pragma unroll
  for (int o = 1; o < 64; o <<= 1) q += __shfl_xor(q, o, 64);
  float rstd = rsqrtf(q * (1.f/128.f) + 1e-5f);
  float n0 = d0 * rstd * gam[t]    + bet[t];
  float n1 = d1 * rstd * gam[t+64] + bet[t+64];
  #pragma unroll
  for (int h = 0; h < 8; ++h) {
    float p = n0 * Wb[t*8 + h] + n1 * Wb[(t+64)*8 + h];
    #pragma unroll
    for (int o = 1; o < 64; o <<= 1) p += __shfl_xor(p, o, 64);
    if (t == h) biasb[((size_t)h*128 + i)*128 + j] = p;
  }
}

// ---------------- kernel 3: weight prep ----------------
// n<1024: Wt[n][k] = W_mat[k][n&255] bf16 (q scaled by 1/sqrt(32))
// n>=1024: WoT[c][k] = Wo[k][c] bf16
__global__ __launch_bounds__(256) void wprep_kernel(
    const float* __restrict__ Wq, const float* __restrict__ Wk,
    const float* __restrict__ Wv, const float* __restrict__ Wg,
    const float* __restrict__ Wo,
    unsigned short* __restrict__ Wt, unsigned short* __restrict__ WoT)
{
  const int n = blockIdx.x, k = threadIdx.x;
  if (n < 1024) {
    const int mat = n >> 8, nl = n & 255;
    const float* W = (mat==0) ? Wq : (mat==1) ? Wk : (mat==2) ? Wv : Wg;
    float v = W[(size_t)k*256 + nl];
    if (mat == 0) v *= 0.17677669529663689f;   // 1/sqrt(32) folded into Wq
    Wt[(size_t)n*256 + k] = f2bf(v);
  } else {
    const int c = n - 1024;
    WoT[(size_t)c*256 + k] = f2bf(Wo[(size_t)k*256 + c]);
  }
}

// ---------------- kernel 4: FUSED QKVG-projection + attention, software-pipelined ----------------
// Block = one l (grid 1024), 512 threads = 8 waves, 144 KB LDS (1 blk/CU).
// Round-5/6: pipeline GEMM(h+1) under softmax(h).
//   region 1: QK(h) | GEMM(h+1) (Xs+wreg only) | W-prefetch(h+2) | softmax | gate preload | P->pbuf
//   BAR_A
//   region 2: epilogue(h+1)->qs/ks/gs,vs[(h+1)&1]  ||  PV(h) from pbuf+vs[h&1] | attn2 store
//   BAR_B
// GEMM MFMAs and softmax VALU share one basic block -> scheduler interleaves (m114 overlap).
// vs double-buffered (PV read || V write); qs/ks/gs single (BAR_A separates).
// Pitches: qs/ks/gs 40 shorts (uniform-bank uint2 writes, floor b128 reads);
// vs 128 (conflict-free chunk-swizzled PV read; r4's 136 broke this).
// h=7 iteration recomputes head 0 branchless (indices &7) — benign, keeps one block.
#define QP 40
__device__ __forceinline__ void gemm_head(
    const unsigned short* Xs, const short8* wreg, int fr, int quad, f32x4* acc)
{
  #pragma unroll
  for (int k0 = 0; k0 < 4; ++k0) {
    #pragma unroll
    for (int kt = 0; kt < 2; ++kt) {
      const int ck = kt*4 + quad;
      const short8 bf = wreg[k0*2 + kt];
      #pragma unroll
      for (int mt = 0; mt < 8; ++mt) {
        const int r = mt*16 + fr;
        short8 af = *(const short8*)(Xs + k0*8192 + r*64 + ((ck^(r&7)))*8);
        acc[mt] = mfma16(bf, af, acc[mt]);   // swapped: fr->m, quad*4+reg->d
      }
    }
  }
}

__device__ __forceinline__ void epilogue_head(
    const f32x4* acc, int mat, int fr, int quad, int dh, int hh,
    unsigned short* qs, unsigned short* ks, unsigned short* gs, unsigned short* vnxt,
    const float* __restrict__ bg)
{
  const int d0 = dh + quad*4;
  if (mat == 2) {           // V: transposed chunk-swizzled [d][128]
    #pragma unroll
    for (int mt = 0; mt < 8; ++mt) {
      const int m = mt*16 + fr;
      #pragma unroll
      for (int reg = 0; reg < 4; ++reg) {
        const int d = d0 + reg;
        vnxt[d*128 + (((m>>3)^(d&7))<<3) + (m&7)] = f2bf(acc[mt][reg]);
      }
    }
  } else {
    unsigned short* buf = (mat==0) ? qs : (mat==1) ? ks : gs;
    float4 b4 = {0.f,0.f,0.f,0.f};
    if (mat == 3) b4 = *(const float4*)(bg + hh*32 + d0);
    #pragma unroll
    for (int mt = 0; mt < 8; ++mt) {
      const int m = mt*16 + fr;
      float v0 = acc[mt][0], v1 = acc[mt][1], v2 = acc[mt][2], v3 = acc[mt][3];
      if (mat == 3) {
        v0 = 1.f/(1.f + __expf(-(v0 + b4.x)));
        v1 = 1.f/(1.f + __expf(-(v1 + b4.y)));
        v2 = 1.f/(1.f + __expf(-(v2 + b4.z)));
        v3 = 1.f/(1.f + __expf(-(v3 + b4.w)));
      }
      uint2 pk;
      pk.x = cvt_pk_bf16(v0, v1);
      pk.y = cvt_pk_bf16(v2, v3);
      *(uint2*)(buf + m*QP + d0) = pk;
    }
  }
}

__global__ __launch_bounds__(512, 2) void fused_qkvg_attn(
    const unsigned short* __restrict__ X, const unsigned short* __restrict__ Wt,
    const float* __restrict__ bg, const float* __restrict__ biasb,
    unsigned short* __restrict__ attn2)
{
  __shared__ __align__(16) unsigned short lds[73728];   // 144 KB
  unsigned short* Xs  = lds;                 // [4 k0][128 r][64 k]    32768
  unsigned short* qs  = lds + 32768;         // [128 m][QP]             5120
  unsigned short* ks  = lds + 37888;         // [128 m][QP]             5120
  unsigned short* gs  = lds + 43008;         // [128 m][QP]             5120
  unsigned short* vsb = lds + 48128;         // 2 x [32 d][128]         8192
  unsigned short* pbuf= lds + 56320;         // 8 waves x [16][136]    17408

  const int t = threadIdx.x, l = blockIdx.x;
  const int w = t>>6, fr = t&15, quad = (t>>4)&3;
  const int mat = w>>1, dh = (w&1)*16;
  unsigned short* pw = pbuf + w*2176;
  const int rbase = w*16;
  const f32x4 zero4 = {0.f,0.f,0.f,0.f};

  // stage Xs once (linear LDS dest, XOR swizzle folded into global src)
  #pragma unroll
  for (int s = 0; s < 8; ++s) {
    int cid = s*512 + t;
    int k0b = cid>>10, r = (cid>>3)&127, pch = cid&7;
    int c = pch ^ (r&7);
    const unsigned short* g = X + ((size_t)l*128 + r)*256 + k0b*64 + c*8;
    GLOAD_LDS16(g, Xs + (cid & ~63)*8);
  }

  // this wave's weight slice: rows mat*256 + h*32 + dh + fr, k-chunk quad*8
  const unsigned short* wptr = Wt + ((size_t)(mat*256 + dh + fr))*256 + quad*8;
  short8 wreg[8];
  #pragma unroll
  for (int i = 0; i < 8; ++i)
    wreg[i] = *(const short8*)(wptr + (i>>1)*64 + (i&1)*32);

  __syncthreads();    // Xs + W(0) ready

  // ---- prologue: project head 0 ----
  {
    f32x4 acc[8] = {};
    gemm_head(Xs, wreg, fr, quad, acc);
    #pragma unroll
    for (int i = 0; i < 8; ++i)          // prefetch W(1)
      wreg[i] = *(const short8*)(wptr + 8192 + (i>>1)*64 + (i&1)*32);
    epilogue_head(acc, mat, fr, quad, dh, 0, qs, ks, gs, vsb, bg);
  }
  __syncthreads();

  for (int h = 0; h < 8; ++h) {
    unsigned short* vcur = vsb + (h&1)*4096;
    unsigned short* vnxt = vsb + ((h+1)&1)*4096;

    // ================= region 1 =================
    // QK^T (head h)
    short8 aq = *(const short8*)(qs + (rbase+fr)*QP + quad*8);
    f32x4 S[8];
    #pragma unroll
    for (int nt=0;nt<8;++nt) {
      short8 bk = *(const short8*)(ks + (nt*16+fr)*QP + quad*8);
      S[nt] = mfma16(aq, bk, zero4);
    }
    // GEMM head h+1 (reads only Xs + wreg) — interleaves with softmax below
    f32x4 acc[8] = {};
    gemm_head(Xs, wreg, fr, quad, acc);
    // prefetch W((h+2)&7) — consumed next iteration
    {
      const unsigned short* wp = wptr + (size_t)((h+2)&7)*8192;
      #pragma unroll
      for (int i = 0; i < 8; ++i)
        wreg[i] = *(const short8*)(wp + (i>>1)*64 + (i&1)*32);
    }
    // bias + softmax (VALU — independent of GEMM above)
    const float* bb = biasb + ((size_t)h*128 + rbase + quad*4)*128 + fr;
    #pragma unroll
    for (int nt=0;nt<8;++nt)
      #pragma unroll
      for (int reg=0;reg<4;++reg)
        S[nt][reg] += bb[(size_t)reg*128 + nt*16];
    float mx[4] = {-1e30f,-1e30f,-1e30f,-1e30f};
    #pragma unroll
    for (int nt=0;nt<8;++nt)
      #pragma unroll
      for (int reg=0;reg<4;++reg) mx[reg] = fmaxf(mx[reg], S[nt][reg]);
    #pragma unroll
    for (int reg=0;reg<4;++reg) {
      mx[reg] = fmaxf(mx[reg], __shfl_xor(mx[reg], 1, 64));
      mx[reg] = fmaxf(mx[reg], __shfl_xor(mx[reg], 2, 64));
      mx[reg] = fmaxf(mx[reg], __shfl_xor(mx[reg], 4, 64));
      mx[reg] = fmaxf(mx[reg], __shfl_xor(mx[reg], 8, 64));
    }
    float sum[4] = {0.f,0.f,0.f,0.f};
    #pragma unroll
    for (int nt=0;nt<8;++nt)
      #pragma unroll
      for (int reg=0;reg<4;++reg) {
        float e = __expf(S[nt][reg]-mx[reg]);
        S[nt][reg] = e; sum[reg] += e;
      }
    #pragma unroll
    for (int reg=0;reg<4;++reg) {
      sum[reg] += __shfl_xor(sum[reg], 1, 64);
      sum[reg] += __shfl_xor(sum[reg], 2, 64);
      sum[reg] += __shfl_xor(sum[reg], 4, 64);
      sum[reg] += __shfl_xor(sum[reg], 8, 64);
    }
    float inv[4];
    #pragma unroll
    for (int reg=0;reg<4;++reg) inv[reg] = 1.f/sum[reg];
    // gate preload (gs holds head h; overwritten after BAR_A)
    float gv[2][4];
    #pragma unroll
    for (int n2=0;n2<2;++n2)
      #pragma unroll
      for (int reg=0;reg<4;++reg)
        gv[n2][reg] = bf1(gs[(rbase + quad*4 + reg)*QP + n2*16 + fr]);
    // P -> pbuf (wave-private; BAR_A drains lgkm)
    #pragma unroll
    for (int nt=0;nt<8;++nt)
      #pragma unroll
      for (int reg=0;reg<4;++reg)
        pw[(quad*4+reg)*136 + nt*16 + fr] = f2bf(S[nt][reg]*inv[reg]);

    __syncthreads();   // BAR_A

    // ================= region 2 =================
    // epilogue head h+1 (writes qs/ks/gs + vnxt) — overlaps PV below
    epilogue_head(acc, mat, fr, quad, dh, (h+1)&7, qs, ks, gs, vnxt, bg);
    // PV (head h): pbuf x vcur
    f32x4 o[2] = {zero4, zero4};
    #pragma unroll
    for (int kt=0;kt<4;++kt) {
      short8 ap = *(const short8*)(pw + fr*136 + kt*32 + quad*8);
      #pragma unroll
      for (int n2=0;n2<2;++n2) {
        const int d = n2*16 + fr;
        const int ph = (kt*4+quad) ^ (d&7);
        short8 bv = *(const short8*)(vcur + d*128 + ph*8);
        o[n2] = mfma16(ap, bv, o[n2]);
      }
    }
    #pragma unroll
    for (int n2=0;n2<2;++n2)
      #pragma unroll
      for (int reg=0;reg<4;++reg) {
        const int row = rbase + quad*4 + reg, col = n2*16 + fr;
        attn2[((size_t)row*1024 + l)*256 + h*32 + col] = f2bf(o[n2][reg]*gv[n2][reg]);
      }

    __syncthreads();   // BAR_B
  }
}

// ---------------- kernel 6: MFMA outproj: out[c][n][l] = Σ_k WoT[c][k]·attn2[n][l][k] + bo[c] ----------------
__global__ __launch_bounds__(256) void outproj_mfma(
    const unsigned short* __restrict__ attn2, const unsigned short* __restrict__ WoT,
    const float* __restrict__ bo, float* __restrict__ out)
{
  __shared__ __align__(16) unsigned short As[128*64], Bs[128*64];
  const int t = threadIdx.x;
  const int c0 = blockIdx.x*128;      // 2 tiles over d_m
  const int l0 = blockIdx.y*128;      // 8 tiles over L
  const int n  = blockIdx.z;          // 128
  const int w = t>>6, lane = t&63, fr = lane&15, quad = lane>>4;
  const int wm = (w>>1)*64, wn = (w&1)*64;
  f32x4 acc[4][4] = {};
  for (int k0 = 0; k0 < 256; k0 += 64) {
    if (k0) __syncthreads();
    #pragma unroll
    for (int pss = 0; pss < 4; ++pss) {
      int s = pss*256 + t;
      int row = s >> 3, pch = s & 7;
      int c = pch ^ (row & 7);
      const unsigned short* ga = WoT   + (size_t)(c0+row)*256 + k0 + c*8;
      const unsigned short* gb = attn2 + ((size_t)n*1024 + l0 + row)*256 + k0 + c*8;
      GLOAD_LDS16(ga, As + (s & ~63)*8);
      GLOAD_LDS16(gb, Bs + (s & ~63)*8);
    }
    __syncthreads();
    #pragma unroll
    for (int kt = 0; kt < 2; ++kt) {
      short8 af[4], bfr[4];
      #pragma unroll
      for (int mt=0;mt<4;++mt){ int r = wm+mt*16+fr; int ch = (kt*4+quad)^(r&7);
        af[mt] = *(const short8*)(As + r*64 + ch*8); }
      #pragma unroll
      for (int nt=0;nt<4;++nt){ int r = wn+nt*16+fr; int ch = (kt*4+quad)^(r&7);
        bfr[nt] = *(const short8*)(Bs + r*64 + ch*8); }
      #pragma unroll
      for (int mt=0;mt<4;++mt)
        #pragma unroll
        for (int nt=0;nt<4;++nt)
          acc[mt][nt] = mfma16(af[mt], bfr[nt], acc[mt][nt]);
    }
  }
  #pragma unroll
  for (int mt=0;mt<4;++mt) {
    #pragma unroll
    for (int reg=0;reg<4;++reg) {
      const int c = c0 + wm + mt*16 + quad*4 + reg;
      const float bv = bo[c];
      #pragma unroll
      for (int nt=0;nt<4;++nt) {
        const int l = l0 + wn + nt*16 + fr;
        out[(size_t)c*131072 + (size_t)n*1024 + l] = acc[mt][nt][reg] + bv;
      }
    }
  }
}

// ---------------- launch ----------------
extern "C" void kernel_launch(void* const* d_in, const int* in_sizes, int n_in,
                              void* d_out, int out_size, void* d_ws, size_t ws_size,
                              hipStream_t stream) {
  const float* msa    = (const float*)d_in[0];
  const float* pairs  = (const float*)d_in[1];
  const float* ln_m_g = (const float*)d_in[2];
  const float* ln_m_b = (const float*)d_in[3];
  const float* ln_p_g = (const float*)d_in[4];
  const float* ln_p_b = (const float*)d_in[5];
  const float* Wq     = (const float*)d_in[6];
  const float* Wk     = (const float*)d_in[7];
  const float* Wv     = (const float*)d_in[8];
  const float* Wg     = (const float*)d_in[9];
  const float* bg     = (const float*)d_in[10];
  const float* Wb     = (const float*)d_in[11];
  const float* Wo     = (const float*)d_in[12];
  const float* bo     = (const float*)d_in[13];
  float* out = (float*)d_out;

  // workspace layout (bytes):
  // attn2 @ 0         : 131072 * 256 * 2     = 64 MiB
  // x16   @ 256 MiB   : 131072 * 256 * 2     = 64 MiB  (LN output; fused input)
  // bias  @ 320 MiB   : 8*128*128*4          = 512 KiB
  // Wt    @ 320.5 MiB : 1024*256*2           = 512 KiB
  // WoT   @ 321 MiB   : 256*256*2            = 128 KiB
  char* ws = (char*)d_ws;
  unsigned short* attn2= (unsigned short*)(ws);
  unsigned short* x16  = (unsigned short*)(ws + (size_t)268435456);
  float*          biasb= (float*)         (ws + (size_t)335544320);
  unsigned short* Wt   = (unsigned short*)(ws + (size_t)336068608);
  unsigned short* WoT  = (unsigned short*)(ws + (size_t)336592896);

  hipLaunchKernelGGL(ln_msa_kernel, dim3(32,128), dim3(256), 0, stream,
                     msa, ln_m_g, ln_m_b, x16);
  hipLaunchKernelGGL(pair_bias_kernel, dim3(128,128), dim3(64), 0, stream,
                     pairs, ln_p_g, ln_p_b, Wb, biasb);
  hipLaunchKernelGGL(wprep_kernel, dim3(1280), dim3(256), 0, stream,
                     Wq, Wk, Wv, Wg, Wo, Wt, WoT);
  hipLaunchKernelGGL(fused_qkvg_attn, dim3(1024), dim3(512), 0, stream,
                     x16, Wt, bg, biasb, attn2);
  hipLaunchKernelGGL(outproj_mfma, dim3(2,8,128), dim3(256), 0, stream,
                     attn2, WoT, bo, out);
}

// Round 7
// 554.713 us; speedup vs baseline: 1.3273x; 1.3273x over previous
//
#include <hip/hip_runtime.h>

// ---------------- helpers ----------------
__device__ __forceinline__ float bf1(unsigned short s){ return __uint_as_float((unsigned)s << 16); }
__device__ __forceinline__ unsigned short f2bf(float f){
  unsigned u = __float_as_uint(f);
  u += 0x7fffu + ((u >> 16) & 1u);   // RNE
  return (unsigned short)(u >> 16);
}
// packed f32x2 -> bf16x2 (lo = a, hi = b), RNE — single VALU instr
__device__ __forceinline__ unsigned cvt_pk_bf16(float a, float b){
  unsigned r;
  asm("v_cvt_pk_bf16_f32 %0, %1, %2" : "=v"(r) : "v"(a), "v"(b));
  return r;
}

typedef __attribute__((ext_vector_type(8))) short short8;
typedef __attribute__((ext_vector_type(4))) float f32x4;

__device__ __forceinline__ f32x4 mfma16(short8 a, short8 b, f32x4 c){
  return __builtin_amdgcn_mfma_f32_16x16x32_bf16(a, b, c, 0, 0, 0);
}

#define GLOAD_LDS16(g, l) \
  __builtin_amdgcn_global_load_lds((const __attribute__((address_space(1))) unsigned int*)(g), \
                                   (__attribute__((address_space(3))) unsigned int*)(l), 16, 0, 0)

// ---------------- kernel 1: LayerNorm over d_m + transpose msa[c][n][l] -> x[l][n][c] (bf16) ----------------
__global__ __launch_bounds__(256) void ln_msa_kernel(
    const float* __restrict__ msa, const float* __restrict__ gam,
    const float* __restrict__ bet, unsigned short* __restrict__ x16)
{
  __shared__ float tile[256*33];          // [c][l] pitch 33
  __shared__ float ps[8*32], pq[8*32];
  __shared__ float mean_s[32], rstd_s[32];
  const int t = threadIdx.x;
  const int l0 = blockIdx.x * 32;
  const int n  = blockIdx.y;
  {
    const int lt = t & 31, ct = t >> 5;
    for (int r = 0; r < 32; ++r) {
      int c = r*8 + ct;
      tile[c*33 + lt] = msa[(size_t)c*131072 + (size_t)n*1024 + l0 + lt];
    }
  }
  __syncthreads();
  {
    const int lt = t & 31, cp = t >> 5;
    float s1 = 0.f, s2 = 0.f;
    for (int cc = 0; cc < 32; ++cc) {
      int c = cp*32 + ((cc + cp*4) & 31);
      float v = tile[c*33 + lt];
      s1 += v; s2 += v*v;
    }
    ps[cp*32 + lt] = s1; pq[cp*32 + lt] = s2;
  }
  __syncthreads();
  if (t < 32) {
    float s1 = 0.f, s2 = 0.f;
    for (int cp = 0; cp < 8; ++cp){ s1 += ps[cp*32+t]; s2 += pq[cp*32+t]; }
    float m = s1 * (1.f/256.f);
    float v = s2 * (1.f/256.f) - m*m;
    mean_s[t] = m;
    rstd_s[t] = rsqrtf(v + 1e-5f);
  }
  __syncthreads();
  {
    const float g = gam[t], b = bet[t];
    for (int l = 0; l < 32; ++l) {
      float v = (tile[t*33 + l] - mean_s[l]) * rstd_s[l] * g + b;
      x16[((size_t)(l0+l)*128 + n)*256 + t] = f2bf(v);
    }
  }
}

// ---------------- kernel 2: pair bias = LN(pairs) @ Wb -> bias[h][i][j] fp32 ----------------
__global__ __launch_bounds__(64) void pair_bias_kernel(
    const float* __restrict__ pairs, const float* __restrict__ gam,
    const float* __restrict__ bet, const float* __restrict__ Wb,
    float* __restrict__ biasb)
{
  const int j = blockIdx.x, i = blockIdx.y;
  const int t = threadIdx.x;
  const float* row = pairs + ((size_t)i*128 + j)*128;
  float v0 = row[t], v1 = row[t+64];
  float s = v0 + v1;
  #pragma unroll
  for (int o = 1; o < 64; o <<= 1) s += __shfl_xor(s, o, 64);
  float m = s * (1.f/128.f);
  float d0 = v0 - m, d1 = v1 - m;
  float q = d0*d0 + d1*d1;
  #pragma unroll
  for (int o = 1; o < 64; o <<= 1) q += __shfl_xor(q, o, 64);
  float rstd = rsqrtf(q * (1.f/128.f) + 1e-5f);
  float n0 = d0 * rstd * gam[t]    + bet[t];
  float n1 = d1 * rstd * gam[t+64] + bet[t+64];
  #pragma unroll
  for (int h = 0; h < 8; ++h) {
    float p = n0 * Wb[t*8 + h] + n1 * Wb[(t+64)*8 + h];
    #pragma unroll
    for (int o = 1; o < 64; o <<= 1) p += __shfl_xor(p, o, 64);
    if (t == h) biasb[((size_t)h*128 + i)*128 + j] = p;
  }
}

// ---------------- kernel 3: weight prep ----------------
// n<1024: Wt[n][k] = W_mat[k][n&255] bf16 (q scaled by 1/sqrt(32))
// n>=1024: WoT[c][k] = Wo[k][c] bf16
__global__ __launch_bounds__(256) void wprep_kernel(
    const float* __restrict__ Wq, const float* __restrict__ Wk,
    const float* __restrict__ Wv, const float* __restrict__ Wg,
    const float* __restrict__ Wo,
    unsigned short* __restrict__ Wt, unsigned short* __restrict__ WoT)
{
  const int n = blockIdx.x, k = threadIdx.x;
  if (n < 1024) {
    const int mat = n >> 8, nl = n & 255;
    const float* W = (mat==0) ? Wq : (mat==1) ? Wk : (mat==2) ? Wv : Wg;
    float v = W[(size_t)k*256 + nl];
    if (mat == 0) v *= 0.17677669529663689f;   // 1/sqrt(32) folded into Wq
    Wt[(size_t)n*256 + k] = f2bf(v);
  } else {
    const int c = n - 1024;
    WoT[(size_t)c*256 + k] = f2bf(Wo[(size_t)k*256 + c]);
  }
}

// ---------------- kernel 4: FUSED QKVG-projection + attention (R3 structure) ----------------
// Block = one l (grid 1024), 512 threads = 8 waves, 160 KB LDS.
// R7 = R3 (best measured) + granule-XOR swizzle on qs/ks/gs:
//   16B granule g of row m stored at g ^ ((m>>1)&3).  Bank math: uint2
//   writes 8-way -> 2-way; aq/bk b128 reads 8-way -> 2-way (fr/fr+8 alias
//   only, free). Zero LDS cost (pitch stays 32; no room for padding at
//   160KB). R4/R6 restructures regressed -> structure reverted to R3.
__global__ __launch_bounds__(512) void fused_qkvg_attn(
    const unsigned short* __restrict__ X, const unsigned short* __restrict__ Wt,
    const float* __restrict__ bg, const float* __restrict__ biasb,
    unsigned short* __restrict__ attn2)
{
  __shared__ __align__(16) unsigned short lds[81920];   // 160 KB exactly
  unsigned short* Xs  = lds;            // 32768 shorts
  unsigned short* Wst = lds + 32768;    // 32768 shorts (aliased by pbuf)
  unsigned short* qs  = lds + 65536;    // 4096
  unsigned short* ks  = lds + 69632;    // 4096
  unsigned short* vs  = lds + 73728;    // 4096
  unsigned short* gs  = lds + 77824;    // 4096

  const int t = threadIdx.x, l = blockIdx.x;
  const int w = t>>6, fr = t&15, quad = (t>>4)&3;
  const int mat = w>>1, dh = (w&1)*16;
  const int d0 = dh + quad*4;
  unsigned short* pw = Wst + w*2176;    // per-wave pbuf [16][136]
  const int rbase = w*16;
  const f32x4 zero4 = {0.f,0.f,0.f,0.f};
  const int frsw = (fr>>1)&3;           // read-side granule swizzle key

  // stage Xs once (linear LDS dest, swizzle folded into global src)
  #pragma unroll
  for (int s = 0; s < 8; ++s) {
    int cid = s*512 + t;
    int k0b = cid>>10, r = (cid>>3)&127, pch = cid&7;
    int c = pch ^ (r&7);
    const unsigned short* g = X + ((size_t)l*128 + r)*256 + k0b*64 + c*8;
    GLOAD_LDS16(g, Xs + (cid & ~63)*8);
  }

  for (int h = 0; h < 8; ++h) {
    // ---- stage per-head weights: rows r=mat*32+d -> Wt[mat*256+h*32+d] ----
    #pragma unroll
    for (int s = 0; s < 8; ++s) {
      int cid = s*512 + t;
      int k0b = cid>>10, r = (cid>>3)&127, pch = cid&7;
      int c = pch ^ (r&7);
      const unsigned short* g = Wt + ((size_t)((r>>5)*256 + h*32 + (r&31)))*256 + k0b*64 + c*8;
      GLOAD_LDS16(g, Wst + (cid & ~63)*8);
    }
    __syncthreads();

    // ---- GEMM: this wave computes all 128 m rows x its 16 d cols ----
    f32x4 acc[8] = {};
    for (int k0 = 0; k0 < 4; ++k0) {
      #pragma unroll
      for (int kt = 0; kt < 2; ++kt) {
        const int ck = kt*4 + quad;
        const int lr = mat*32 + dh + fr;
        short8 bf = *(const short8*)(Wst + k0*8192 + lr*64 + (ck^(lr&7))*8);
        #pragma unroll
        for (int mt = 0; mt < 8; ++mt) {
          const int r = mt*16 + fr;
          short8 af = *(const short8*)(Xs + k0*8192 + r*64 + (ck^(r&7))*8);
          acc[mt] = mfma16(bf, af, acc[mt]);   // swapped: fr->m, quad*4+reg->d
        }
      }
    }

    // ---- epilogue: write Q/K/V/G into attn layouts ----
    if (mat == 2) {           // V: transposed chunk-swizzled [d][128]
      #pragma unroll
      for (int mt = 0; mt < 8; ++mt) {
        const int m = mt*16 + fr;
        #pragma unroll
        for (int reg = 0; reg < 4; ++reg) {
          const int d = d0 + reg;
          vs[d*128 + (((m>>3)^(d&7))<<3) + (m&7)] = f2bf(acc[mt][reg]);
        }
      }
    } else {
      unsigned short* buf = (mat==0) ? qs : (mat==1) ? ks : gs;
      float4 b4;
      if (mat == 3) b4 = *(const float4*)(bg + h*32 + d0);
      #pragma unroll
      for (int mt = 0; mt < 8; ++mt) {
        const int m = mt*16 + fr;
        float v0 = acc[mt][0], v1 = acc[mt][1], v2 = acc[mt][2], v3 = acc[mt][3];
        if (mat == 3) {
          v0 = 1.f/(1.f + __expf(-(v0 + b4.x)));
          v1 = 1.f/(1.f + __expf(-(v1 + b4.y)));
          v2 = 1.f/(1.f + __expf(-(v2 + b4.z)));
          v3 = 1.f/(1.f + __expf(-(v3 + b4.w)));
        }
        uint2 pk;
        pk.x = cvt_pk_bf16(v0, v1);
        pk.y = cvt_pk_bf16(v2, v3);
        // granule-XOR: granule (d0>>3) ^ ((m>>1)&3); uint2 fits in half-granule
        *(uint2*)(buf + m*32 + ((((d0>>3) ^ ((m>>1)&3))<<3)) + (d0&7)) = pk;
      }
    }
    __syncthreads();

    // ---- attn phase ----
    short8 aq = *(const short8*)(qs + (rbase+fr)*32 + ((quad ^ frsw)<<3));
    f32x4 S[8];
    #pragma unroll
    for (int nt=0;nt<8;++nt) {
      short8 bk = *(const short8*)(ks + (nt*16+fr)*32 + ((quad ^ frsw)<<3));
      S[nt] = mfma16(aq, bk, zero4);
    }
    const float* bb = biasb + ((size_t)h*128 + rbase + quad*4)*128 + fr;
    #pragma unroll
    for (int nt=0;nt<8;++nt)
      #pragma unroll
      for (int reg=0;reg<4;++reg)
        S[nt][reg] += bb[(size_t)reg*128 + nt*16];
    float mx[4] = {-1e30f,-1e30f,-1e30f,-1e30f};
    #pragma unroll
    for (int nt=0;nt<8;++nt)
      #pragma unroll
      for (int reg=0;reg<4;++reg) mx[reg] = fmaxf(mx[reg], S[nt][reg]);
    #pragma unroll
    for (int reg=0;reg<4;++reg) {
      mx[reg] = fmaxf(mx[reg], __shfl_xor(mx[reg], 1, 64));
      mx[reg] = fmaxf(mx[reg], __shfl_xor(mx[reg], 2, 64));
      mx[reg] = fmaxf(mx[reg], __shfl_xor(mx[reg], 4, 64));
      mx[reg] = fmaxf(mx[reg], __shfl_xor(mx[reg], 8, 64));
    }
    float sum[4] = {0.f,0.f,0.f,0.f};
    #pragma unroll
    for (int nt=0;nt<8;++nt)
      #pragma unroll
      for (int reg=0;reg<4;++reg) {
        float e = __expf(S[nt][reg]-mx[reg]);
        S[nt][reg] = e; sum[reg] += e;
      }
    #pragma unroll
    for (int reg=0;reg<4;++reg) {
      sum[reg] += __shfl_xor(sum[reg], 1, 64);
      sum[reg] += __shfl_xor(sum[reg], 2, 64);
      sum[reg] += __shfl_xor(sum[reg], 4, 64);
      sum[reg] += __shfl_xor(sum[reg], 8, 64);
    }
    float inv[4];
    #pragma unroll
    for (int reg=0;reg<4;++reg) inv[reg] = 1.f/sum[reg];
    #pragma unroll
    for (int nt=0;nt<8;++nt)
      #pragma unroll
      for (int reg=0;reg<4;++reg)
        pw[(quad*4+reg)*136 + nt*16 + fr] = f2bf(S[nt][reg]*inv[reg]);
    __builtin_amdgcn_s_waitcnt(0);   // wave-private LDS region
    f32x4 o[2] = {zero4, zero4};
    #pragma unroll
    for (int kt=0;kt<4;++kt) {
      short8 ap = *(const short8*)(pw + fr*136 + kt*32 + quad*8);
      #pragma unroll
      for (int n2=0;n2<2;++n2) {
        const int d = n2*16 + fr;
        const int ph = (kt*4+quad) ^ (d&7);
        short8 bv = *(const short8*)(vs + d*128 + ph*8);
        o[n2] = mfma16(ap, bv, o[n2]);
      }
    }
    #pragma unroll
    for (int n2=0;n2<2;++n2)
      #pragma unroll
      for (int reg=0;reg<4;++reg) {
        const int row = rbase + quad*4 + reg, col = n2*16 + fr;
        const int rsw = ((quad*4+reg)>>1)&3;
        const float gv = bf1(gs[row*32 + ((((n2*2)+(fr>>3)) ^ rsw)<<3) + (fr&7)]);
        attn2[((size_t)row*1024 + l)*256 + h*32 + col] = f2bf(o[n2][reg]*gv);
      }
    __syncthreads();
  }
}

// ---------------- kernel 6: MFMA outproj: out[c][n][l] = Σ_k WoT[c][k]·attn2[n][l][k] + bo[c] ----------------
// R7: LDS-bounce epilogue (two 64-row passes through the 32KB staging region)
// -> fully coalesced float4 stores instead of 16 scattered 4B stores/thread.
__global__ __launch_bounds__(256) void outproj_mfma(
    const unsigned short* __restrict__ attn2, const unsigned short* __restrict__ WoT,
    const float* __restrict__ bo, float* __restrict__ out)
{
  __shared__ __align__(16) unsigned short sm[2*128*64];   // As | Bs, reused as f32 out-tile
  unsigned short* As = sm;
  unsigned short* Bs = sm + 128*64;
  const int t = threadIdx.x;
  const int c0 = blockIdx.x*128;      // 2 tiles over d_m
  const int l0 = blockIdx.y*128;      // 8 tiles over L
  const int n  = blockIdx.z;          // 128
  const int w = t>>6, lane = t&63, fr = lane&15, quad = lane>>4;
  const int wm = (w>>1)*64, wn = (w&1)*64;
  f32x4 acc[4][4] = {};
  for (int k0 = 0; k0 < 256; k0 += 64) {
    if (k0) __syncthreads();
    #pragma unroll
    for (int pss = 0; pss < 4; ++pss) {
      int s = pss*256 + t;
      int row = s >> 3, pch = s & 7;
      int c = pch ^ (row & 7);
      const unsigned short* ga = WoT   + (size_t)(c0+row)*256 + k0 + c*8;
      const unsigned short* gb = attn2 + ((size_t)n*1024 + l0 + row)*256 + k0 + c*8;
      GLOAD_LDS16(ga, As + (s & ~63)*8);
      GLOAD_LDS16(gb, Bs + (s & ~63)*8);
    }
    __syncthreads();
    #pragma unroll
    for (int kt = 0; kt < 2; ++kt) {
      short8 af[4], bfr[4];
      #pragma unroll
      for (int mt=0;mt<4;++mt){ int r = wm+mt*16+fr; int ch = (kt*4+quad)^(r&7);
        af[mt] = *(const short8*)(As + r*64 + ch*8); }
      #pragma unroll
      for (int nt=0;nt<4;++nt){ int r = wn+nt*16+fr; int ch = (kt*4+quad)^(r&7);
        bfr[nt] = *(const short8*)(Bs + r*64 + ch*8); }
      #pragma unroll
      for (int mt=0;mt<4;++mt)
        #pragma unroll
        for (int nt=0;nt<4;++nt)
          acc[mt][nt] = mfma16(af[mt], bfr[nt], acc[mt][nt]);
    }
  }
  // ---- LDS-bounce epilogue: two passes of 64 c-rows x 128 l (32KB f32) ----
  __syncthreads();                      // all MFMA reads of As/Bs done
  float* ob = (float*)sm;               // 64 x 128 f32 = 32768 B
  const int hw = w >> 1;                // this wave's c-half
  #pragma unroll
  for (int half = 0; half < 2; ++half) {
    if (hw == half) {
      #pragma unroll
      for (int mt=0;mt<4;++mt)
        #pragma unroll
        for (int nt=0;nt<4;++nt)
          #pragma unroll
          for (int reg=0;reg<4;++reg) {
            const int cl = mt*16 + quad*4 + reg;      // 0..63
            const int ll = wn + nt*16 + fr;           // 0..127
            ob[cl*128 + ll] = acc[mt][nt][reg];
          }
    }
    __syncthreads();
    #pragma unroll
    for (int p = 0; p < 4; ++p) {
      const int id = p*256 + t;          // 1024 float8-chunks
      const int cl = id >> 4, l8 = (id & 15)*8;
      const float4 a = *(const float4*)(ob + cl*128 + l8);
      const float4 b = *(const float4*)(ob + cl*128 + l8 + 4);
      const int c = c0 + half*64 + cl;
      const float bv = bo[c];
      float4 sa = a, sb = b;
      sa.x += bv; sa.y += bv; sa.z += bv; sa.w += bv;
      sb.x += bv; sb.y += bv; sb.z += bv; sb.w += bv;
      float* op = out + (size_t)c*131072 + (size_t)n*1024 + l0 + l8;
      *(float4*)op = sa;
      *(float4*)(op+4) = sb;
    }
    __syncthreads();
  }
}

// ---------------- launch ----------------
extern "C" void kernel_launch(void* const* d_in, const int* in_sizes, int n_in,
                              void* d_out, int out_size, void* d_ws, size_t ws_size,
                              hipStream_t stream) {
  const float* msa    = (const float*)d_in[0];
  const float* pairs  = (const float*)d_in[1];
  const float* ln_m_g = (const float*)d_in[2];
  const float* ln_m_b = (const float*)d_in[3];
  const float* ln_p_g = (const float*)d_in[4];
  const float* ln_p_b = (const float*)d_in[5];
  const float* Wq     = (const float*)d_in[6];
  const float* Wk     = (const float*)d_in[7];
  const float* Wv     = (const float*)d_in[8];
  const float* Wg     = (const float*)d_in[9];
  const float* bg     = (const float*)d_in[10];
  const float* Wb     = (const float*)d_in[11];
  const float* Wo     = (const float*)d_in[12];
  const float* bo     = (const float*)d_in[13];
  float* out = (float*)d_out;

  // workspace layout (bytes):
  // attn2 @ 0         : 131072 * 256 * 2     = 64 MiB
  // x16   @ 256 MiB   : 131072 * 256 * 2     = 64 MiB  (LN output; fused input)
  // bias  @ 320 MiB   : 8*128*128*4          = 512 KiB
  // Wt    @ 320.5 MiB : 1024*256*2           = 512 KiB
  // WoT   @ 321 MiB   : 256*256*2            = 128 KiB
  char* ws = (char*)d_ws;
  unsigned short* attn2= (unsigned short*)(ws);
  unsigned short* x16  = (unsigned short*)(ws + (size_t)268435456);
  float*          biasb= (float*)         (ws + (size_t)335544320);
  unsigned short* Wt   = (unsigned short*)(ws + (size_t)336068608);
  unsigned short* WoT  = (unsigned short*)(ws + (size_t)336592896);

  hipLaunchKernelGGL(ln_msa_kernel, dim3(32,128), dim3(256), 0, stream,
                     msa, ln_m_g, ln_m_b, x16);
  hipLaunchKernelGGL(pair_bias_kernel, dim3(128,128), dim3(64), 0, stream,
                     pairs, ln_p_g, ln_p_b, Wb, biasb);
  hipLaunchKernelGGL(wprep_kernel, dim3(1280), dim3(256), 0, stream,
                     Wq, Wk, Wv, Wg, Wo, Wt, WoT);
  hipLaunchKernelGGL(fused_qkvg_attn, dim3(1024), dim3(512), 0, stream,
                     x16, Wt, bg, biasb, attn2);
  hipLaunchKernelGGL(outproj_mfma, dim3(2,8,128), dim3(256), 0, stream,
                     attn2, WoT, bo, out);
}